// Round 1
// baseline (2623.638 us; speedup 1.0000x reference)
//
#include <hip/hip_runtime.h>

// ---------------------------------------------------------------------------
// PCAA: B=4, C=K=512, H=W=128, BIN=4x4 -> bins=16, rH=rW=32, P=1024, Ci=256.
// All fp32. Workspace layout (floats):
//   conf  @ 0         : 33,554,432  (cam logits -> pixel_conf; later aff; later y)
//   localb@ 33554432  : 16,777,216  (local -> lfeats -> query -> attn_out)
//   gbuf  @ 50331648  : 16,777,216  (g; later key uses first 8,388,608)
//   glob  @ 67108864  :  1,048,576
//   vt    @ 68157440  :    524,288  (value transposed [b][i][k])
//   bc    @ 68681728  :     32,768  (sigmoid(bin pooled) = bin confidence)
// total 68,714,496 floats = 262.1 MiB
// x gather: bin n=(nh,nw): addr(b,c,p) = b*8388608 + c*16384
//                                        + (nh*32 + p/32)*128 + nw*32 + (p%32)
// ---------------------------------------------------------------------------

#define TS 64
#define KT 16

// NT GEMM: out[m][n] = sum_kk A[m][kk] * B[n][kk]  (lda = ldb = Kd)
// AMODE: 0 = plain row-major; 1 = A[m=p][kk=c] gathered from x (patch layout)
// BMODE: 0 = plain row-major; 1 = B[n=p][kk=c] gathered from x;
//        2 = B[n=c][kk=p] gathered from x
template<int AMODE, int BMODE>
__global__ void __launch_bounds__(256) gemm_nt(
    const float* __restrict__ Aptr, int aBatch,
    const float* __restrict__ Bptr, int bBatch, int bShift,
    float* __restrict__ Cptr, int cBatch,
    int M, int N, int Kd,
    const float* __restrict__ biasM,
    const float* __restrict__ biasN,
    const float* __restrict__ scaleM)
{
    __shared__ float As[KT][TS + 4];
    __shared__ float Bs[KT][TS + 4];
    const int t  = threadIdx.x;
    const int bt = blockIdx.z;
    const int m0 = blockIdx.y * TS;
    const int n0 = blockIdx.x * TS;

    int xbase = 0;
    if (AMODE != 0 || BMODE != 0) {
        const int b = bt >> 4, n = bt & 15;
        xbase = b * 8388608 + (n >> 2) * 4096 + (n & 3) * 32;
    }
    const float* Ab = Aptr + (AMODE == 0 ? bt * aBatch : 0);
    const float* Bb = Bptr + (BMODE == 0 ? (bt >> bShift) * bBatch : 0);

    float acc[4][4];
#pragma unroll
    for (int i = 0; i < 4; ++i)
#pragma unroll
        for (int j = 0; j < 4; ++j) acc[i][j] = 0.f;

    const int p_kq  = (t & 3) * 4;   // plain load: kk quad
    const int p_row = t >> 2;        // plain load: row within tile
    const int g_kk  = t >> 4;        // gather KKC: kk (=c)
    const int g_i4  = (t & 15) * 4;  // gather KKC: idx (=p) quad

    for (int k0 = 0; k0 < Kd; k0 += KT) {
        // ---- A tile -> As[kk][m] ----
        if (AMODE == 0) {
            const float4 v = *(const float4*)(Ab + (m0 + p_row) * Kd + k0 + p_kq);
            As[p_kq + 0][p_row] = v.x;
            As[p_kq + 1][p_row] = v.y;
            As[p_kq + 2][p_row] = v.z;
            As[p_kq + 3][p_row] = v.w;
        } else {
            const int c = k0 + g_kk;
            const int p = m0 + g_i4;
            const float4 v = *(const float4*)(Aptr + xbase + c * 16384 + ((p >> 5) << 7) + (p & 31));
            *(float4*)&As[g_kk][g_i4] = v;
        }
        // ---- B tile -> Bs[kk][n] ----
        if (BMODE == 0) {
            const float4 v = *(const float4*)(Bb + (n0 + p_row) * Kd + k0 + p_kq);
            Bs[p_kq + 0][p_row] = v.x;
            Bs[p_kq + 1][p_row] = v.y;
            Bs[p_kq + 2][p_row] = v.z;
            Bs[p_kq + 3][p_row] = v.w;
        } else if (BMODE == 1) {
            const int c = k0 + g_kk;
            const int p = n0 + g_i4;
            const float4 v = *(const float4*)(Bptr + xbase + c * 16384 + ((p >> 5) << 7) + (p & 31));
            *(float4*)&Bs[g_kk][g_i4] = v;
        } else {
            const int p    = k0 + (t & 15);
            const int poff = ((p >> 5) << 7) + (p & 31);
#pragma unroll
            for (int q = 0; q < 4; ++q) {
                const int c = n0 + (t >> 4) + q * 16;
                Bs[t & 15][(t >> 4) + q * 16] = Bptr[xbase + c * 16384 + poff];
            }
        }
        __syncthreads();
#pragma unroll
        for (int kk = 0; kk < KT; ++kk) {
            const float4 av = *(const float4*)&As[kk][(t >> 4) * 4];
            const float4 bv = *(const float4*)&Bs[kk][(t & 15) * 4];
            const float a[4] = {av.x, av.y, av.z, av.w};
            const float b[4] = {bv.x, bv.y, bv.z, bv.w};
#pragma unroll
            for (int i = 0; i < 4; ++i)
#pragma unroll
                for (int j = 0; j < 4; ++j)
                    acc[i][j] = fmaf(a[i], b[j], acc[i][j]);
        }
        __syncthreads();
    }

    float* Cb = Cptr + bt * cBatch;
#pragma unroll
    for (int i = 0; i < 4; ++i) {
        const int m = m0 + (t >> 4) * 4 + i;
        const float bm = biasM ? biasM[m] : 0.f;
        const float sm = scaleM ? scaleM[bt * M + m] : 1.f;
#pragma unroll
        for (int j = 0; j < 4; ++j) {
            const int n = n0 + (t & 15) * 4 + j;
            const float v = acc[i][j] + bm + (biasN ? biasN[n] : 0.f);
            Cb[m * N + n] = v * sm;
        }
    }
}

// per-row (1024) softmax over pixels (in place) + bin pooled mean -> sigmoid
__global__ void __launch_bounds__(256) softmax_pool_1024(
    float* __restrict__ conf, float* __restrict__ binconf)
{
    const int row = blockIdx.x;             // bn*512 + k
    float* r = conf + row * 1024;
    const int t = threadIdx.x;
    float4 v = *(const float4*)(r + t * 4);
    float s  = v.x + v.y + v.z + v.w;
    float mx = fmaxf(fmaxf(v.x, v.y), fmaxf(v.z, v.w));
#pragma unroll
    for (int off = 32; off > 0; off >>= 1) {
        s += __shfl_down(s, off, 64);
        mx = fmaxf(mx, __shfl_down(mx, off, 64));
    }
    __shared__ float rs[4], rm[4], re[4];
    const int wv = t >> 6, ln = t & 63;
    if (ln == 0) { rs[wv] = s; rm[wv] = mx; }
    __syncthreads();
    const float MX = fmaxf(fmaxf(rm[0], rm[1]), fmaxf(rm[2], rm[3]));
    if (t == 0) {
        const float mean = (rs[0] + rs[1] + rs[2] + rs[3]) * (1.f / 1024.f);
        binconf[row] = 1.f / (1.f + __expf(-mean));
    }
    float4 e;
    e.x = __expf(v.x - MX); e.y = __expf(v.y - MX);
    e.z = __expf(v.z - MX); e.w = __expf(v.w - MX);
    float es = e.x + e.y + e.z + e.w;
#pragma unroll
    for (int off = 32; off > 0; off >>= 1) es += __shfl_down(es, off, 64);
    if (ln == 0) re[wv] = es;
    __syncthreads();
    const float inv = 1.f / (re[0] + re[1] + re[2] + re[3]);
    e.x *= inv; e.y *= inv; e.z *= inv; e.w *= inv;
    *(float4*)(r + t * 4) = e;
}

// softmax over last dim (512), one wave per row, in place
__global__ void __launch_bounds__(256) softmax_rows_512(float* __restrict__ aff)
{
    const int t = threadIdx.x;
    const int wv = t >> 6, ln = t & 63;
    const int row = blockIdx.x * 4 + wv;
    float* r = aff + row * 512;
    float4 a = *(const float4*)(r + ln * 4);
    float4 b = *(const float4*)(r + 256 + ln * 4);
    float mx = fmaxf(fmaxf(fmaxf(a.x, a.y), fmaxf(a.z, a.w)),
                     fmaxf(fmaxf(b.x, b.y), fmaxf(b.z, b.w)));
#pragma unroll
    for (int off = 32; off > 0; off >>= 1) mx = fmaxf(mx, __shfl_down(mx, off, 64));
    mx = __shfl(mx, 0, 64);
    a.x = __expf(a.x - mx); a.y = __expf(a.y - mx);
    a.z = __expf(a.z - mx); a.w = __expf(a.w - mx);
    b.x = __expf(b.x - mx); b.y = __expf(b.y - mx);
    b.z = __expf(b.z - mx); b.w = __expf(b.w - mx);
    float es = a.x + a.y + a.z + a.w + b.x + b.y + b.z + b.w;
#pragma unroll
    for (int off = 32; off > 0; off >>= 1) es += __shfl_down(es, off, 64);
    es = __shfl(es, 0, 64);
    const float inv = 1.f / es;
    a.x *= inv; a.y *= inv; a.z *= inv; a.w *= inv;
    b.x *= inv; b.y *= inv; b.z *= inv; b.w *= inv;
    *(float4*)(r + ln * 4) = a;
    *(float4*)(r + 256 + ln * 4) = b;
}

// g[b][n][k][c] = relu(sum_m w1[n][m]*local[b][m][k][c] + local[b][n][k][c])
__global__ void __launch_bounds__(256) gcn1_kernel(
    const float* __restrict__ localb, float* __restrict__ g,
    const float* __restrict__ w_gcn1)
{
    __shared__ float w[16][16];
    const int t = threadIdx.x;
    w[t >> 4][t & 15] = w_gcn1[t];
    const int idx = blockIdx.x * 256 + t;
    const int b  = idx >> 18;           // K*C = 262144
    const int kc = idx & 262143;
    const float* lp = localb + b * 4194304 + kc;
    __syncthreads();
    float lv[16];
#pragma unroll
    for (int m = 0; m < 16; ++m) lv[m] = lp[m * 262144];
    float* gp = g + b * 4194304 + kc;
#pragma unroll
    for (int n = 0; n < 16; ++n) {
        float acc = lv[n];
#pragma unroll
        for (int m = 0; m < 16; ++m) acc = fmaf(w[n][m], lv[m], acc);
        gp[n * 262144] = fmaxf(acc, 0.f);
    }
}

// glob[b][k][c] = relu(sum_m w_fuse[m]*lfeats[b][m][k][c] + b_fuse)
__global__ void __launch_bounds__(256) glob_kernel(
    const float* __restrict__ lfeats, float* __restrict__ glob,
    const float* __restrict__ w_fuse, const float* __restrict__ b_fuse)
{
    const int idx = blockIdx.x * 256 + threadIdx.x;
    const int b  = idx >> 18;
    const int kc = idx & 262143;
    const float* lp = lfeats + b * 4194304 + kc;
    float acc = b_fuse[0];
#pragma unroll
    for (int m = 0; m < 16; ++m) acc = fmaf(w_fuse[m], lp[m * 262144], acc);
    glob[idx] = fmaxf(acc, 0.f);
}

// out = x + relu(bn(y)), y in [bn][c][p] patch layout, out in NCHW
__global__ void __launch_bounds__(256) bn_residual(
    const float* __restrict__ y, const float* __restrict__ x,
    float* __restrict__ out,
    const float* __restrict__ gam, const float* __restrict__ bet,
    const float* __restrict__ mu, const float* __restrict__ var)
{
    const int i4 = (blockIdx.x * 256 + threadIdx.x) * 4;
    const int w = i4 & 127, h = (i4 >> 7) & 127, c = (i4 >> 14) & 511, b = i4 >> 23;
    const int p  = (h & 31) * 32 + (w & 31);
    const int bn = b * 16 + ((h >> 5) << 2) + (w >> 5);
    const float4 yv = *(const float4*)(y + (bn * 512 + c) * 1024 + p);
    const float4 xv = *(const float4*)(x + i4);
    const float sc = gam[c] * rsqrtf(var[c] + 1e-5f);
    const float mm = mu[c], bb = bet[c];
    float4 o;
    o.x = xv.x + fmaxf(fmaf(yv.x - mm, sc, bb), 0.f);
    o.y = xv.y + fmaxf(fmaf(yv.y - mm, sc, bb), 0.f);
    o.z = xv.z + fmaxf(fmaf(yv.z - mm, sc, bb), 0.f);
    o.w = xv.w + fmaxf(fmaf(yv.w - mm, sc, bb), 0.f);
    *(float4*)(out + i4) = o;
}

extern "C" void kernel_launch(void* const* d_in, const int* in_sizes, int n_in,
                              void* d_out, int out_size, void* d_ws, size_t ws_size,
                              hipStream_t stream) {
    (void)in_sizes; (void)n_in; (void)out_size; (void)ws_size;
    const float* x      = (const float*)d_in[0];
    const float* w_cam  = (const float*)d_in[1];
    const float* b_cam  = (const float*)d_in[2];
    const float* w_gcn1 = (const float*)d_in[3];
    const float* w_gcn2 = (const float*)d_in[4];
    const float* w_fuse = (const float*)d_in[5];
    const float* b_fuse = (const float*)d_in[6];
    const float* w_q    = (const float*)d_in[7];
    const float* b_q    = (const float*)d_in[8];
    const float* w_k    = (const float*)d_in[9];
    const float* b_k    = (const float*)d_in[10];
    const float* w_v    = (const float*)d_in[11];
    const float* b_v    = (const float*)d_in[12];
    const float* w_out  = (const float*)d_in[13];
    const float* bng    = (const float*)d_in[14];
    const float* bnb    = (const float*)d_in[15];
    const float* bnm    = (const float*)d_in[16];
    const float* bnv    = (const float*)d_in[17];

    float* ws     = (float*)d_ws;
    float* conf   = ws;               // 33,554,432 (cam/conf -> aff -> y)
    float* localb = ws + 33554432;    // 16,777,216 (local -> lfeats -> query -> attn)
    float* gbuf   = ws + 50331648;    // 16,777,216 (g -> key)
    float* glob   = ws + 67108864;    //  1,048,576
    float* vt     = ws + 68157440;    //    524,288
    float* bc     = ws + 68681728;    //     32,768
    float* aff    = conf;
    float* ybuf   = conf;
    float* lfeats = localb;
    float* query  = localb;
    float* attn   = localb;
    float* key    = gbuf;

    // 1) cam[bn][k][p] = w_cam @ x_bin + b_cam          (M=512,N=1024,Kd=512)
    gemm_nt<0, 1><<<dim3(16, 8, 64), 256, 0, stream>>>(
        w_cam, 0, x, 0, 0, conf, 524288, 512, 1024, 512, b_cam, nullptr, nullptr);
    // 2) pixel softmax over p (in place) + bin_conf = sigmoid(mean_p)
    softmax_pool_1024<<<32768, 256, 0, stream>>>(conf, bc);
    // 3) local[bn][k][c] = (conf @ x_bin^T) * bin_conf  (M=512,N=512,Kd=1024)
    gemm_nt<0, 2><<<dim3(8, 8, 64), 256, 0, stream>>>(
        conf, 524288, x, 0, 0, localb, 262144, 512, 512, 1024, nullptr, nullptr, bc);
    // 4) g = relu(w_gcn1 @ local + local)
    gcn1_kernel<<<4096, 256, 0, stream>>>(localb, gbuf, w_gcn1);
    // 5) lfeats[bnk][d] = g @ w_gcn2^T                  (M=32768,N=512,Kd=512)
    gemm_nt<0, 0><<<dim3(8, 512, 1), 256, 0, stream>>>(
        gbuf, 0, w_gcn2, 0, 0, lfeats, 0, 32768, 512, 512, nullptr, nullptr, nullptr);
    // 6) glob[b][k][c] = relu(w_fuse . lfeats + b_fuse)
    glob_kernel<<<4096, 256, 0, stream>>>(lfeats, glob, w_fuse, b_fuse);
    // 7) vt[b][i][k] = w_v @ glob^T + b_v               (M=256,N=512,Kd=512)
    gemm_nt<0, 0><<<dim3(8, 4, 4), 256, 0, stream>>>(
        w_v, 0, glob, 262144, 0, vt, 131072, 256, 512, 512, b_v, nullptr, nullptr);
    // 8) key[bnk][i] = lfeats @ w_k^T + b_k             (M=32768,N=256,Kd=512)
    gemm_nt<0, 0><<<dim3(4, 512, 1), 256, 0, stream>>>(
        lfeats, 0, w_k, 0, 0, key, 0, 32768, 256, 512, nullptr, b_k, nullptr);
    // 9) query[bn][p][i] = x_bin^T @ w_q^T + b_q        (M=1024,N=256,Kd=512)
    gemm_nt<1, 0><<<dim3(4, 16, 64), 256, 0, stream>>>(
        x, 0, w_q, 0, 0, query, 262144, 1024, 256, 512, nullptr, b_q, nullptr);
    // 10) aff[bn][p][k] = query @ key^T                 (M=1024,N=512,Kd=256)
    gemm_nt<0, 0><<<dim3(8, 16, 64), 256, 0, stream>>>(
        query, 262144, key, 131072, 0, aff, 524288, 1024, 512, 256, nullptr, nullptr, nullptr);
    // 11) softmax over k (in place)
    softmax_rows_512<<<16384, 256, 0, stream>>>(aff);
    // 12) attn[bn][p][i] = aff @ vt[b]^T                (M=1024,N=256,Kd=512)
    gemm_nt<0, 0><<<dim3(4, 16, 64), 256, 0, stream>>>(
        aff, 524288, vt, 131072, 4, attn, 262144, 1024, 256, 512, nullptr, nullptr, nullptr);
    // 13) y[bn][c][p] = w_out @ attn^T                  (M=512,N=1024,Kd=256)
    gemm_nt<0, 0><<<dim3(16, 8, 64), 256, 0, stream>>>(
        w_out, 0, attn, 262144, 0, ybuf, 524288, 512, 1024, 256, nullptr, nullptr, nullptr);
    // 14) out = x + relu(bn(y))
    bn_residual<<<32768, 256, 0, stream>>>(ybuf, x, (float*)d_out, bng, bnb, bnm, bnv);
}

// Round 2
// 820.457 us; speedup vs baseline: 3.1978x; 3.1978x over previous
//
#include <hip/hip_runtime.h>
#include <hip/hip_bf16.h>
#include <stdint.h>

// ---------------------------------------------------------------------------
// PCAA bf16-MFMA version. B=4, C=K=512, H=W=128, bins=16, rH=rW=32, P=1024,
// Ci=256. All GEMMs run on one bf16 MFMA kernel (NT: out[m][n]=sum_k A[m][k]
// B[n][k]), fp32 accumulate, bf16 outputs, fp32 bias/scale epilogues.
//
// Workspace (byte offsets; ws_size >= 274,857,984 B from round 1):
//   0           wbf (6 weight mats bf16, 2,097,152 B)
//   2,097,152   bc  (32768 f32, 131,072 B)
//   2,228,224   xpc [bn][p][c] bf16, 67,108,864 B          (live: conv..G9)
//   69,337,088  xcp [bn][c][p] bf16, 67,108,864 B          (live: conv..G3)
//       reuse:  g    @69,337,088  (33.5MB, gcn1..G5)
//               lf   @102,891,520 (33.5MB, G5..G8)   attn reuses lf (G12..G13)
//   136,445,952 confb [bn][k][p] bf16 67,108,864 B         (live: G1..G3)
//       reuse:  globb @136,445,952 (2MB)   vt @138,543,104 (0.5MB)
//               key  @139,067,392 (16.8MB) query @155,844,608 (33.5MB)
//               ybuf @136,445,952 (67MB, G13..bn)
//   203,554,816 localb bf16 33,554,432 B -> ends 237,109,248  (peak)
//   aff reuses xpc region (G10..G12).
// ---------------------------------------------------------------------------

typedef __attribute__((ext_vector_type(8))) short bfrag;
typedef __attribute__((ext_vector_type(4))) float ffrag;
typedef __hip_bfloat16 bf16;

__device__ __forceinline__ void load_lds16(const void* g, void* l) {
    // CK idiom: generic->AS1 via uintptr_t; generic LDS ptr low 32 bits = LDS
    // offset, AS3 pointers are 32-bit.
    __builtin_amdgcn_global_load_lds(
        (const __attribute__((address_space(1))) void*)(uintptr_t)g,
        (__attribute__((address_space(3))) void*)(uintptr_t)l,
        16, 0, 0);
}

// NT bf16 MFMA GEMM: C[bt][m][n] = sum_k A[m][k]*B[n][k] (+biasM[m]+biasN[n])
// (*scaleM[bt*M+m]).  128x128 tile, BK=64, 4 waves each computing 64x64.
// LDS rows are 128 B (8 chunks of 16 B); chunk XOR-swizzled by (row&7) so the
// frag ds_read_b128s hit all 32 banks uniformly (8 words/bank = minimum).
__global__ void __launch_bounds__(256) gemm_bf16(
    const short* __restrict__ A, int aBatch,
    const short* __restrict__ B, int bBatch, int bShift,
    short* __restrict__ C, int cBatch,
    int M, int N, int K,
    const float* __restrict__ biasM, const float* __restrict__ biasN,
    const float* __restrict__ scaleM)
{
    __shared__ short As[128 * 64];
    __shared__ short Bs[128 * 64];
    const int t = threadIdx.x;
    const int w = t >> 6, lane = t & 63;
    const int bt = blockIdx.z;
    const int m0 = blockIdx.y * 128, n0 = blockIdx.x * 128;
    const short* gA = A + (size_t)bt * aBatch;
    const short* gB = B + (size_t)(bt >> bShift) * bBatch;
    const int wm = w >> 1, wn = w & 1;

    ffrag acc[4][4] = {};

    const int rowbase = w * 32;             // this wave stages 32 rows per tile
    const int lr = lane >> 3;               // row-in-load
    const int lc = lane & 7;                // physical 16B chunk

    for (int k0 = 0; k0 < K; k0 += 64) {
#pragma unroll
        for (int j = 0; j < 4; ++j) {
            const int rr = rowbase + j * 8 + lr;      // tile row
            const int ch = lc ^ (rr & 7);             // logical chunk fetched
            load_lds16(gA + (size_t)(m0 + rr) * K + k0 + ch * 8,
                       &As[(rowbase + j * 8) * 64]);  // wave-uniform LDS base
            load_lds16(gB + (size_t)(n0 + rr) * K + k0 + ch * 8,
                       &Bs[(rowbase + j * 8) * 64]);
        }
        __syncthreads();
#pragma unroll
        for (int kk = 0; kk < 2; ++kk) {
            bfrag af[4], bfv[4];
#pragma unroll
            for (int i = 0; i < 4; ++i) {
                const int ra = wm * 64 + i * 16 + (lane & 15);
                const int cl = kk * 4 + (lane >> 4);
                af[i]  = *(const bfrag*)&As[ra * 64 + ((cl ^ (ra & 7)) * 8)];
                const int rb = wn * 64 + i * 16 + (lane & 15);
                bfv[i] = *(const bfrag*)&Bs[rb * 64 + ((cl ^ (rb & 7)) * 8)];
            }
#pragma unroll
            for (int i = 0; i < 4; ++i)
#pragma unroll
                for (int j = 0; j < 4; ++j)
                    acc[i][j] = __builtin_amdgcn_mfma_f32_16x16x32_bf16(
                        af[i], bfv[j], acc[i][j], 0, 0, 0);
        }
        __syncthreads();
    }

    bf16* gC = (bf16*)(C + (size_t)bt * cBatch);
#pragma unroll
    for (int i = 0; i < 4; ++i) {
#pragma unroll
        for (int j = 0; j < 4; ++j) {
            const int col = n0 + wn * 64 + j * 16 + (lane & 15);
            const float bnv = biasN ? biasN[col] : 0.f;
#pragma unroll
            for (int r = 0; r < 4; ++r) {
                const int row = m0 + wm * 64 + i * 16 + (lane >> 4) * 4 + r;
                float v = acc[i][j][r] + bnv + (biasM ? biasM[row] : 0.f);
                if (scaleM) v *= scaleM[bt * M + row];
                gC[(size_t)row * N + col] = __float2bfloat16(v);
            }
        }
    }
}

// fp32 -> bf16 for the 6 weight matrices, packed contiguously into wbf.
__global__ void __launch_bounds__(256) wconv(
    const float* __restrict__ wc, const float* __restrict__ wg2,
    const float* __restrict__ wq, const float* __restrict__ wk,
    const float* __restrict__ wv, const float* __restrict__ wo,
    bf16* __restrict__ dst)
{
    const int i = blockIdx.x * 256 + threadIdx.x;   // 1,048,576 total
    const float* s; int o;
    if      (i <  262144) { s = wc;  o = i; }
    else if (i <  524288) { s = wg2; o = i - 262144; }
    else if (i <  655360) { s = wq;  o = i - 524288; }
    else if (i <  786432) { s = wk;  o = i - 655360; }
    else if (i <  917504) { s = wv;  o = i - 786432; }
    else                  { s = wo;  o = i - 917504; }
    dst[i] = __float2bfloat16(s[o]);
}

// x NCHW fp32 -> xpc[bn][p][c] bf16 and xcp[bn][c][p] bf16 (LDS transpose).
__global__ void __launch_bounds__(256) convert_x(
    const float* __restrict__ x, bf16* __restrict__ xpc, bf16* __restrict__ xcp)
{
    const int bn = blockIdx.x, ct = blockIdx.y, pt = blockIdx.z;
    const int b = bn >> 4, n = bn & 15;
    const int c0 = ct * 32, p0 = pt * 32;
    const int h = (n >> 2) * 32 + pt;       // one h-row per 32-wide p tile
    const int w0 = (n & 3) * 32;
    __shared__ float tile[32][33];
    const int t = threadIdx.x;
    const int pw = t & 31, ci = t >> 5;     // ci in 0..7
#pragma unroll
    for (int i = 0; i < 4; ++i) {
        const int c = c0 + ci + i * 8;
        const float v = x[(((size_t)b * 512 + c) * 128 + h) * 128 + w0 + pw];
        tile[ci + i * 8][pw] = v;
        xcp[((size_t)bn * 512 + c) * 1024 + p0 + pw] = __float2bfloat16(v);
    }
    __syncthreads();
    const int pi = t >> 5, cc = t & 31;
#pragma unroll
    for (int i = 0; i < 4; ++i) {
        const int p = p0 + pi + i * 8;
        xpc[((size_t)bn * 1024 + p) * 512 + c0 + cc] =
            __float2bfloat16(tile[cc][pi + i * 8]);
    }
}

// per-row (1024 px) softmax in place on bf16 + binconf = sigmoid(mean)
__global__ void __launch_bounds__(256) softmax_pool_1024(
    bf16* __restrict__ conf, float* __restrict__ binconf)
{
    const int row = blockIdx.x;             // bn*512 + k
    bf16* r = conf + (size_t)row * 1024;
    const int t = threadIdx.x;
    bf16 a[4];
    *(uint2*)a = *(const uint2*)(r + t * 4);
    float f[4];
#pragma unroll
    for (int i = 0; i < 4; ++i) f[i] = __bfloat162float(a[i]);
    float s  = f[0] + f[1] + f[2] + f[3];
    float mx = fmaxf(fmaxf(f[0], f[1]), fmaxf(f[2], f[3]));
#pragma unroll
    for (int off = 32; off > 0; off >>= 1) {
        s += __shfl_down(s, off, 64);
        mx = fmaxf(mx, __shfl_down(mx, off, 64));
    }
    __shared__ float rs[4], rm[4], re[4];
    const int wv = t >> 6, ln = t & 63;
    if (ln == 0) { rs[wv] = s; rm[wv] = mx; }
    __syncthreads();
    const float MX = fmaxf(fmaxf(rm[0], rm[1]), fmaxf(rm[2], rm[3]));
    if (t == 0) {
        const float mean = (rs[0] + rs[1] + rs[2] + rs[3]) * (1.f / 1024.f);
        binconf[row] = 1.f / (1.f + __expf(-mean));
    }
    float e[4];
#pragma unroll
    for (int i = 0; i < 4; ++i) e[i] = __expf(f[i] - MX);
    float es = e[0] + e[1] + e[2] + e[3];
#pragma unroll
    for (int off = 32; off > 0; off >>= 1) es += __shfl_down(es, off, 64);
    if (ln == 0) re[wv] = es;
    __syncthreads();
    const float inv = 1.f / (re[0] + re[1] + re[2] + re[3]);
#pragma unroll
    for (int i = 0; i < 4; ++i) a[i] = __float2bfloat16(e[i] * inv);
    *(uint2*)(r + t * 4) = *(uint2*)a;
}

// softmax over last dim (512), one wave per row, in place, bf16
__global__ void __launch_bounds__(256) softmax_rows_512(bf16* __restrict__ aff)
{
    const int t = threadIdx.x;
    const int wv = t >> 6, ln = t & 63;
    const int row = blockIdx.x * 4 + wv;
    bf16* r = aff + (size_t)row * 512;
    bf16 a[8];
    *(uint4*)a = *(const uint4*)(r + ln * 8);
    float f[8];
#pragma unroll
    for (int i = 0; i < 8; ++i) f[i] = __bfloat162float(a[i]);
    float mx = f[0];
#pragma unroll
    for (int i = 1; i < 8; ++i) mx = fmaxf(mx, f[i]);
#pragma unroll
    for (int off = 32; off > 0; off >>= 1) mx = fmaxf(mx, __shfl_down(mx, off, 64));
    mx = __shfl(mx, 0, 64);
    float es = 0.f;
#pragma unroll
    for (int i = 0; i < 8; ++i) { f[i] = __expf(f[i] - mx); es += f[i]; }
#pragma unroll
    for (int off = 32; off > 0; off >>= 1) es += __shfl_down(es, off, 64);
    es = __shfl(es, 0, 64);
    const float inv = 1.f / es;
#pragma unroll
    for (int i = 0; i < 8; ++i) a[i] = __float2bfloat16(f[i] * inv);
    *(uint4*)(r + ln * 8) = *(uint4*)a;
}

// g[b][n][k][c] = relu(sum_m w1[n][m]*local[b][m][k][c] + local[b][n][k][c])
__global__ void __launch_bounds__(256) gcn1_kernel(
    const bf16* __restrict__ localb, bf16* __restrict__ g,
    const float* __restrict__ w_gcn1)
{
    __shared__ float wsm[16][16];
    const int t = threadIdx.x;
    wsm[t >> 4][t & 15] = w_gcn1[t];
    const int idx = blockIdx.x * 256 + t;
    const int b  = idx >> 18;               // K*C = 262144
    const int kc = idx & 262143;
    const bf16* lp = localb + (size_t)b * 4194304 + kc;
    __syncthreads();
    float lv[16];
#pragma unroll
    for (int m = 0; m < 16; ++m) lv[m] = __bfloat162float(lp[m * 262144]);
    bf16* gp = g + (size_t)b * 4194304 + kc;
#pragma unroll
    for (int n = 0; n < 16; ++n) {
        float acc = lv[n];
#pragma unroll
        for (int m = 0; m < 16; ++m) acc = fmaf(wsm[n][m], lv[m], acc);
        gp[n * 262144] = __float2bfloat16(fmaxf(acc, 0.f));
    }
}

// glob[b][k][c] = relu(sum_m w_fuse[m]*lfeats[b][m][k][c] + b_fuse)
__global__ void __launch_bounds__(256) glob_kernel(
    const bf16* __restrict__ lfeats, bf16* __restrict__ glob,
    const float* __restrict__ w_fuse, const float* __restrict__ b_fuse)
{
    const int idx = blockIdx.x * 256 + threadIdx.x;
    const int b  = idx >> 18;
    const int kc = idx & 262143;
    const bf16* lp = lfeats + (size_t)b * 4194304 + kc;
    float acc = b_fuse[0];
#pragma unroll
    for (int m = 0; m < 16; ++m)
        acc = fmaf(w_fuse[m], __bfloat162float(lp[m * 262144]), acc);
    glob[idx] = __float2bfloat16(fmaxf(acc, 0.f));
}

// out = x + relu(bn(y)), y bf16 in [bn][c][p] patch layout, out fp32 NCHW
__global__ void __launch_bounds__(256) bn_residual(
    const bf16* __restrict__ y, const float* __restrict__ x,
    float* __restrict__ out,
    const float* __restrict__ gam, const float* __restrict__ bet,
    const float* __restrict__ mu, const float* __restrict__ var)
{
    const int i4 = (blockIdx.x * 256 + threadIdx.x) * 4;
    const int w = i4 & 127, h = (i4 >> 7) & 127, c = (i4 >> 14) & 511, b = i4 >> 23;
    const int p  = (h & 31) * 32 + (w & 31);
    const int bn = b * 16 + ((h >> 5) << 2) + (w >> 5);
    bf16 yv[4];
    *(uint2*)yv = *(const uint2*)(y + ((size_t)bn * 512 + c) * 1024 + p);
    const float4 xv = *(const float4*)(x + i4);
    const float sc = gam[c] * rsqrtf(var[c] + 1e-5f);
    const float mm = mu[c], bb = bet[c];
    float4 o;
    o.x = xv.x + fmaxf(fmaf(__bfloat162float(yv[0]) - mm, sc, bb), 0.f);
    o.y = xv.y + fmaxf(fmaf(__bfloat162float(yv[1]) - mm, sc, bb), 0.f);
    o.z = xv.z + fmaxf(fmaf(__bfloat162float(yv[2]) - mm, sc, bb), 0.f);
    o.w = xv.w + fmaxf(fmaf(__bfloat162float(yv[3]) - mm, sc, bb), 0.f);
    *(float4*)(out + i4) = o;
}

extern "C" void kernel_launch(void* const* d_in, const int* in_sizes, int n_in,
                              void* d_out, int out_size, void* d_ws, size_t ws_size,
                              hipStream_t stream) {
    (void)in_sizes; (void)n_in; (void)out_size; (void)ws_size;
    const float* x      = (const float*)d_in[0];
    const float* w_cam  = (const float*)d_in[1];
    const float* b_cam  = (const float*)d_in[2];
    const float* w_gcn1 = (const float*)d_in[3];
    const float* w_gcn2 = (const float*)d_in[4];
    const float* w_fuse = (const float*)d_in[5];
    const float* b_fuse = (const float*)d_in[6];
    const float* w_q    = (const float*)d_in[7];
    const float* b_q    = (const float*)d_in[8];
    const float* w_k    = (const float*)d_in[9];
    const float* b_k    = (const float*)d_in[10];
    const float* w_v    = (const float*)d_in[11];
    const float* b_v    = (const float*)d_in[12];
    const float* w_out  = (const float*)d_in[13];
    const float* bng    = (const float*)d_in[14];
    const float* bnb    = (const float*)d_in[15];
    const float* bnm    = (const float*)d_in[16];
    const float* bnv    = (const float*)d_in[17];

    char* base = (char*)d_ws;
    bf16*  wbf    = (bf16*)(base);
    float* bc     = (float*)(base + 2097152);
    bf16*  xpc    = (bf16*)(base + 2228224);
    bf16*  xcp    = (bf16*)(base + 69337088);
    bf16*  confb  = (bf16*)(base + 136445952);
    bf16*  localb = (bf16*)(base + 203554816);
    bf16*  g      = xcp;                        // xcp dead after G3
    bf16*  lf     = (bf16*)(base + 102891520);  // second half of xcp region
    bf16*  globb  = confb;                      // confb dead after G3
    bf16*  vt     = (bf16*)(base + 138543104);
    bf16*  key    = (bf16*)(base + 139067392);
    bf16*  query  = (bf16*)(base + 155844608);
    bf16*  aff    = xpc;                        // xpc dead after G9
    bf16*  attn   = lf;                         // lf dead after G8
    bf16*  ybuf   = confb;                      // key/query/vt dead after G12

    bf16* wcam = wbf;
    bf16* wg2  = wbf + 262144;
    bf16* wq   = wbf + 524288;
    bf16* wk   = wbf + 655360;
    bf16* wv   = wbf + 786432;
    bf16* wo   = wbf + 917504;

    wconv<<<4096, 256, 0, stream>>>(w_cam, w_gcn2, w_q, w_k, w_v, w_out, wbf);
    convert_x<<<dim3(64, 16, 32), 256, 0, stream>>>(x, xpc, xcp);

    // 1) cam[bn][k][p] = w_cam . xpc + b_cam     M=512 N=1024 K=512 z=64
    gemm_bf16<<<dim3(8, 4, 64), 256, 0, stream>>>(
        (const short*)wcam, 0, (const short*)xpc, 524288, 0,
        (short*)confb, 524288, 512, 1024, 512, b_cam, nullptr, nullptr);
    // 2) pixel softmax (in place) + bin confidence
    softmax_pool_1024<<<32768, 256, 0, stream>>>(confb, bc);
    // 3) local[bn][k][c] = (conf . xcp) * bc     M=512 N=512 K=1024
    gemm_bf16<<<dim3(4, 4, 64), 256, 0, stream>>>(
        (const short*)confb, 524288, (const short*)xcp, 524288, 0,
        (short*)localb, 262144, 512, 512, 1024, nullptr, nullptr, bc);
    // 4) g = relu(w_gcn1 @ local + local)
    gcn1_kernel<<<4096, 256, 0, stream>>>(localb, g, w_gcn1);
    // 5) lfeats[bnk][d] = g . w_gcn2             M=32768 N=512 K=512
    gemm_bf16<<<dim3(4, 256, 1), 256, 0, stream>>>(
        (const short*)g, 0, (const short*)wg2, 0, 0,
        (short*)lf, 0, 32768, 512, 512, nullptr, nullptr, nullptr);
    // 6) glob = relu(w_fuse . lfeats + b_fuse)
    glob_kernel<<<4096, 256, 0, stream>>>(lf, globb, w_fuse, b_fuse);
    // 7) vt[b][i][k] = w_v . glob + b_v          M=256 N=512 K=512 z=4
    gemm_bf16<<<dim3(4, 2, 4), 256, 0, stream>>>(
        (const short*)wv, 0, (const short*)globb, 262144, 0,
        (short*)vt, 131072, 256, 512, 512, b_v, nullptr, nullptr);
    // 8) key[bnk][i] = lfeats . w_k + b_k        M=32768 N=256 K=512
    gemm_bf16<<<dim3(2, 256, 1), 256, 0, stream>>>(
        (const short*)lf, 0, (const short*)wk, 0, 0,
        (short*)key, 0, 32768, 256, 512, nullptr, b_k, nullptr);
    // 9) query[bn][p][i] = xpc . w_q + b_q       M=1024 N=256 K=512 z=64
    gemm_bf16<<<dim3(2, 8, 64), 256, 0, stream>>>(
        (const short*)xpc, 524288, (const short*)wq, 0, 0,
        (short*)query, 262144, 1024, 256, 512, nullptr, b_q, nullptr);
    // 10) aff[bn][p][k] = query . key            M=1024 N=512 K=256 z=64
    gemm_bf16<<<dim3(4, 8, 64), 256, 0, stream>>>(
        (const short*)query, 262144, (const short*)key, 131072, 0,
        (short*)aff, 524288, 1024, 512, 256, nullptr, nullptr, nullptr);
    // 11) softmax over k (in place)
    softmax_rows_512<<<16384, 256, 0, stream>>>(aff);
    // 12) attn[bn][p][i] = aff . vt[b]           M=1024 N=256 K=512 z=64
    gemm_bf16<<<dim3(2, 8, 64), 256, 0, stream>>>(
        (const short*)aff, 524288, (const short*)vt, 131072, 4,
        (short*)attn, 262144, 1024, 256, 512, nullptr, nullptr, nullptr);
    // 13) y[bn][c][p] = w_out . attn             M=512 N=1024 K=256 z=64
    gemm_bf16<<<dim3(8, 4, 64), 256, 0, stream>>>(
        (const short*)wo, 0, (const short*)attn, 262144, 0,
        (short*)ybuf, 524288, 512, 1024, 256, nullptr, nullptr, nullptr);
    // 14) out = x + relu(bn(y))
    bn_residual<<<32768, 256, 0, stream>>>(ybuf, x, (float*)d_out, bng, bnb, bnm, bnv);
}

// Round 3
// 769.410 us; speedup vs baseline: 3.4099x; 1.0663x over previous
//
#include <hip/hip_runtime.h>
#include <hip/hip_bf16.h>
#include <stdint.h>

// ---------------------------------------------------------------------------
// PCAA bf16-MFMA, round 3: XCD-aware block swizzle + BN/residual fused into
// the final GEMM epilogue. B=4, C=K=512, H=W=128, bins=16, P=1024, Ci=256.
//
// Workspace (byte offsets):
//   0           wbf (6 weight mats bf16, 2,097,152 B)
//   2,097,152   bc  (32768 f32)
//   2,228,224   xpc [bn][p][c] bf16, 67,108,864 B   (live: conv..G9; aff after)
//   69,337,088  xcp [bn][c][p] bf16, 67,108,864 B   (live: conv..G3)
//       reuse:  g @69,337,088 (33.5MB) | lf @102,891,520 (33.5MB; attn later)
//   136,445,952 confb [bn][k][p] bf16 67MB (G1..G3); then globb/vt/key/query
//   203,554,816 localb bf16 33,554,432 B
// ---------------------------------------------------------------------------

typedef __attribute__((ext_vector_type(8))) short bfrag;
typedef __attribute__((ext_vector_type(4))) float ffrag;
typedef __hip_bfloat16 bf16;

__device__ __forceinline__ void load_lds16(const void* g, void* l) {
    __builtin_amdgcn_global_load_lds(
        (const __attribute__((address_space(1))) void*)(uintptr_t)g,
        (__attribute__((address_space(3))) void*)(uintptr_t)l,
        16, 0, 0);
}

// NT bf16 MFMA GEMM, 128x128 tile, BK=64, 4 waves of 64x64.
// 1D swizzled grid (see decode below): bins of a batch-z GEMM are pinned to
// one XCD (id%8 round-robin) so a bin's ~2MB working set stays in its L2;
// z==1 GEMMs group m-strips per XCD instead.
// EPI=0: bf16 out (+biasM/biasN, *scaleM).  EPI=1: BN+ReLU+residual, fp32
// NCHW out (G13: m=c, n=p, bt=bn).
template<int EPI>
__global__ void __launch_bounds__(256) gemm_bf16(
    const short* __restrict__ A, int aBatch,
    const short* __restrict__ B, int bBatch, int bShift,
    short* __restrict__ C, int cBatch,
    int M, int N, int K, int mT, int nT, int zTotal,
    const float* __restrict__ biasM, const float* __restrict__ biasN,
    const float* __restrict__ scaleM,
    const float* __restrict__ xres,
    const float* __restrict__ bng, const float* __restrict__ bnb,
    const float* __restrict__ bnm, const float* __restrict__ bnv)
{
    __shared__ short As[128 * 64];
    __shared__ short Bs[128 * 64];
    const int t = threadIdx.x;
    const int w = t >> 6, lane = t & 63;

    // ---- swizzled block decode ----
    const int id = blockIdx.x;
    const int T = mT * nT;
    int bt, mt, nt;
    if (zTotal >= 8) {                 // bin-per-XCD grouping (zTotal%8==0)
        const int x = id & 7, q = id >> 3;
        const int tile = q % T;
        bt = (q / T) * 8 + x;
        mt = tile / nT; nt = tile % nT;
    } else if (zTotal == 1 && (mT & 7) == 0) {  // m-strip-per-XCD grouping
        const int x = id & 7, q = id >> 3;
        nt = q % nT;
        mt = x * (mT >> 3) + q / nT;
        bt = 0;
    } else {
        bt = id / T;
        const int tile = id % T;
        mt = tile / nT; nt = tile % nT;
    }
    const int m0 = mt * 128, n0 = nt * 128;

    const short* gA = A + (size_t)bt * aBatch;
    const short* gB = B + (size_t)(bt >> bShift) * bBatch;
    const int wm = w >> 1, wn = w & 1;

    ffrag acc[4][4] = {};

    const int rowbase = w * 32;
    const int lr = lane >> 3;
    const int lc = lane & 7;

    for (int k0 = 0; k0 < K; k0 += 64) {
#pragma unroll
        for (int j = 0; j < 4; ++j) {
            const int rr = rowbase + j * 8 + lr;
            const int ch = lc ^ (rr & 7);
            load_lds16(gA + (size_t)(m0 + rr) * K + k0 + ch * 8,
                       &As[(rowbase + j * 8) * 64]);
            load_lds16(gB + (size_t)(n0 + rr) * K + k0 + ch * 8,
                       &Bs[(rowbase + j * 8) * 64]);
        }
        __syncthreads();
#pragma unroll
        for (int kk = 0; kk < 2; ++kk) {
            bfrag af[4], bfv[4];
#pragma unroll
            for (int i = 0; i < 4; ++i) {
                const int ra = wm * 64 + i * 16 + (lane & 15);
                const int cl = kk * 4 + (lane >> 4);
                af[i]  = *(const bfrag*)&As[ra * 64 + ((cl ^ (ra & 7)) * 8)];
                const int rb = wn * 64 + i * 16 + (lane & 15);
                bfv[i] = *(const bfrag*)&Bs[rb * 64 + ((cl ^ (rb & 7)) * 8)];
            }
#pragma unroll
            for (int i = 0; i < 4; ++i)
#pragma unroll
                for (int j = 0; j < 4; ++j)
                    acc[i][j] = __builtin_amdgcn_mfma_f32_16x16x32_bf16(
                        af[i], bfv[j], acc[i][j], 0, 0, 0);
        }
        __syncthreads();
    }

    if (EPI == 0) {
        bf16* gC = (bf16*)(C + (size_t)bt * cBatch);
#pragma unroll
        for (int i = 0; i < 4; ++i) {
#pragma unroll
            for (int j = 0; j < 4; ++j) {
                const int col = n0 + wn * 64 + j * 16 + (lane & 15);
                const float bnvl = biasN ? biasN[col] : 0.f;
#pragma unroll
                for (int r = 0; r < 4; ++r) {
                    const int row = m0 + wm * 64 + i * 16 + (lane >> 4) * 4 + r;
                    float v = acc[i][j][r] + bnvl + (biasM ? biasM[row] : 0.f);
                    if (scaleM) v *= scaleM[bt * M + row];
                    gC[(size_t)row * N + col] = __float2bfloat16(v);
                }
            }
        }
    } else {
        // G13: rows = c, cols = p, bt = bn. out = x + relu(bn(acc)), fp32 NCHW.
        float* O = (float*)C;
        const int b = bt >> 4, binq = bt & 15;
        const int h0 = (binq >> 2) * 32, w0 = (binq & 3) * 32;
#pragma unroll
        for (int i = 0; i < 4; ++i) {
#pragma unroll
            for (int r = 0; r < 4; ++r) {
                const int c = m0 + wm * 64 + i * 16 + (lane >> 4) * 4 + r;
                const float sc = bng[c] * rsqrtf(bnv[c] + 1e-5f);
                const float mm = bnm[c], bb = bnb[c];
#pragma unroll
                for (int j = 0; j < 4; ++j) {
                    const int p = n0 + wn * 64 + j * 16 + (lane & 15);
                    const size_t flat =
                        (((size_t)b * 512 + c) * 128 + h0 + (p >> 5)) * 128
                        + w0 + (p & 31);
                    O[flat] = xres[flat]
                        + fmaxf(fmaf(acc[i][j][r] - mm, sc, bb), 0.f);
                }
            }
        }
    }
}

// fp32 -> bf16 for the 6 weight matrices, packed contiguously into wbf.
__global__ void __launch_bounds__(256) wconv(
    const float* __restrict__ wc, const float* __restrict__ wg2,
    const float* __restrict__ wq, const float* __restrict__ wk,
    const float* __restrict__ wv, const float* __restrict__ wo,
    bf16* __restrict__ dst)
{
    const int i = blockIdx.x * 256 + threadIdx.x;   // 1,048,576 total
    const float* s; int o;
    if      (i <  262144) { s = wc;  o = i; }
    else if (i <  524288) { s = wg2; o = i - 262144; }
    else if (i <  655360) { s = wq;  o = i - 524288; }
    else if (i <  786432) { s = wk;  o = i - 655360; }
    else if (i <  917504) { s = wv;  o = i - 786432; }
    else                  { s = wo;  o = i - 917504; }
    dst[i] = __float2bfloat16(s[o]);
}

// x NCHW fp32 -> xpc[bn][p][c] bf16 and xcp[bn][c][p] bf16 (LDS transpose).
__global__ void __launch_bounds__(256) convert_x(
    const float* __restrict__ x, bf16* __restrict__ xpc, bf16* __restrict__ xcp)
{
    const int bn = blockIdx.x, ct = blockIdx.y, pt = blockIdx.z;
    const int b = bn >> 4, n = bn & 15;
    const int c0 = ct * 32, p0 = pt * 32;
    const int h = (n >> 2) * 32 + pt;
    const int w0 = (n & 3) * 32;
    __shared__ float tile[32][33];
    const int t = threadIdx.x;
    const int pw = t & 31, ci = t >> 5;
#pragma unroll
    for (int i = 0; i < 4; ++i) {
        const int c = c0 + ci + i * 8;
        const float v = x[(((size_t)b * 512 + c) * 128 + h) * 128 + w0 + pw];
        tile[ci + i * 8][pw] = v;
        xcp[((size_t)bn * 512 + c) * 1024 + p0 + pw] = __float2bfloat16(v);
    }
    __syncthreads();
    const int pi = t >> 5, cc = t & 31;
#pragma unroll
    for (int i = 0; i < 4; ++i) {
        const int p = p0 + pi + i * 8;
        xpc[((size_t)bn * 1024 + p) * 512 + c0 + cc] =
            __float2bfloat16(tile[cc][pi + i * 8]);
    }
}

// per-row (1024 px) softmax in place on bf16 + binconf = sigmoid(mean)
__global__ void __launch_bounds__(256) softmax_pool_1024(
    bf16* __restrict__ conf, float* __restrict__ binconf)
{
    const int row = blockIdx.x;             // bn*512 + k
    bf16* r = conf + (size_t)row * 1024;
    const int t = threadIdx.x;
    bf16 a[4];
    *(uint2*)a = *(const uint2*)(r + t * 4);
    float f[4];
#pragma unroll
    for (int i = 0; i < 4; ++i) f[i] = __bfloat162float(a[i]);
    float s  = f[0] + f[1] + f[2] + f[3];
    float mx = fmaxf(fmaxf(f[0], f[1]), fmaxf(f[2], f[3]));
#pragma unroll
    for (int off = 32; off > 0; off >>= 1) {
        s += __shfl_down(s, off, 64);
        mx = fmaxf(mx, __shfl_down(mx, off, 64));
    }
    __shared__ float rs[4], rm[4], re[4];
    const int wv = t >> 6, ln = t & 63;
    if (ln == 0) { rs[wv] = s; rm[wv] = mx; }
    __syncthreads();
    const float MX = fmaxf(fmaxf(rm[0], rm[1]), fmaxf(rm[2], rm[3]));
    if (t == 0) {
        const float mean = (rs[0] + rs[1] + rs[2] + rs[3]) * (1.f / 1024.f);
        binconf[row] = 1.f / (1.f + __expf(-mean));
    }
    float e[4];
#pragma unroll
    for (int i = 0; i < 4; ++i) e[i] = __expf(f[i] - MX);
    float es = e[0] + e[1] + e[2] + e[3];
#pragma unroll
    for (int off = 32; off > 0; off >>= 1) es += __shfl_down(es, off, 64);
    if (ln == 0) re[wv] = es;
    __syncthreads();
    const float inv = 1.f / (re[0] + re[1] + re[2] + re[3]);
#pragma unroll
    for (int i = 0; i < 4; ++i) a[i] = __float2bfloat16(e[i] * inv);
    *(uint2*)(r + t * 4) = *(uint2*)a;
}

// softmax over last dim (512), one wave per row, in place, bf16
__global__ void __launch_bounds__(256) softmax_rows_512(bf16* __restrict__ aff)
{
    const int t = threadIdx.x;
    const int wv = t >> 6, ln = t & 63;
    const int row = blockIdx.x * 4 + wv;
    bf16* r = aff + (size_t)row * 512;
    bf16 a[8];
    *(uint4*)a = *(const uint4*)(r + ln * 8);
    float f[8];
#pragma unroll
    for (int i = 0; i < 8; ++i) f[i] = __bfloat162float(a[i]);
    float mx = f[0];
#pragma unroll
    for (int i = 1; i < 8; ++i) mx = fmaxf(mx, f[i]);
#pragma unroll
    for (int off = 32; off > 0; off >>= 1) mx = fmaxf(mx, __shfl_down(mx, off, 64));
    mx = __shfl(mx, 0, 64);
    float es = 0.f;
#pragma unroll
    for (int i = 0; i < 8; ++i) { f[i] = __expf(f[i] - mx); es += f[i]; }
#pragma unroll
    for (int off = 32; off > 0; off >>= 1) es += __shfl_down(es, off, 64);
    es = __shfl(es, 0, 64);
    const float inv = 1.f / es;
#pragma unroll
    for (int i = 0; i < 8; ++i) a[i] = __float2bfloat16(f[i] * inv);
    *(uint4*)(r + ln * 8) = *(uint4*)a;
}

// g[b][n][k][c] = relu(sum_m w1[n][m]*local[b][m][k][c] + local[b][n][k][c])
__global__ void __launch_bounds__(256) gcn1_kernel(
    const bf16* __restrict__ localb, bf16* __restrict__ g,
    const float* __restrict__ w_gcn1)
{
    __shared__ float wsm[16][16];
    const int t = threadIdx.x;
    wsm[t >> 4][t & 15] = w_gcn1[t];
    const int idx = blockIdx.x * 256 + t;
    const int b  = idx >> 18;               // K*C = 262144
    const int kc = idx & 262143;
    const bf16* lp = localb + (size_t)b * 4194304 + kc;
    __syncthreads();
    float lv[16];
#pragma unroll
    for (int m = 0; m < 16; ++m) lv[m] = __bfloat162float(lp[m * 262144]);
    bf16* gp = g + (size_t)b * 4194304 + kc;
#pragma unroll
    for (int n = 0; n < 16; ++n) {
        float acc = lv[n];
#pragma unroll
        for (int m = 0; m < 16; ++m) acc = fmaf(wsm[n][m], lv[m], acc);
        gp[n * 262144] = __float2bfloat16(fmaxf(acc, 0.f));
    }
}

// glob[b][k][c] = relu(sum_m w_fuse[m]*lfeats[b][m][k][c] + b_fuse)
__global__ void __launch_bounds__(256) glob_kernel(
    const bf16* __restrict__ lfeats, bf16* __restrict__ glob,
    const float* __restrict__ w_fuse, const float* __restrict__ b_fuse)
{
    const int idx = blockIdx.x * 256 + threadIdx.x;
    const int b  = idx >> 18;
    const int kc = idx & 262143;
    const bf16* lp = lfeats + (size_t)b * 4194304 + kc;
    float acc = b_fuse[0];
#pragma unroll
    for (int m = 0; m < 16; ++m)
        acc = fmaf(w_fuse[m], __bfloat162float(lp[m * 262144]), acc);
    glob[idx] = __float2bfloat16(fmaxf(acc, 0.f));
}

extern "C" void kernel_launch(void* const* d_in, const int* in_sizes, int n_in,
                              void* d_out, int out_size, void* d_ws, size_t ws_size,
                              hipStream_t stream) {
    (void)in_sizes; (void)n_in; (void)out_size; (void)ws_size;
    const float* x      = (const float*)d_in[0];
    const float* w_cam  = (const float*)d_in[1];
    const float* b_cam  = (const float*)d_in[2];
    const float* w_gcn1 = (const float*)d_in[3];
    const float* w_gcn2 = (const float*)d_in[4];
    const float* w_fuse = (const float*)d_in[5];
    const float* b_fuse = (const float*)d_in[6];
    const float* w_q    = (const float*)d_in[7];
    const float* b_q    = (const float*)d_in[8];
    const float* w_k    = (const float*)d_in[9];
    const float* b_k    = (const float*)d_in[10];
    const float* w_v    = (const float*)d_in[11];
    const float* b_v    = (const float*)d_in[12];
    const float* w_out  = (const float*)d_in[13];
    const float* bng    = (const float*)d_in[14];
    const float* bnb    = (const float*)d_in[15];
    const float* bnm    = (const float*)d_in[16];
    const float* bnv    = (const float*)d_in[17];

    char* base = (char*)d_ws;
    bf16*  wbf    = (bf16*)(base);
    float* bc     = (float*)(base + 2097152);
    bf16*  xpc    = (bf16*)(base + 2228224);
    bf16*  xcp    = (bf16*)(base + 69337088);
    bf16*  confb  = (bf16*)(base + 136445952);
    bf16*  localb = (bf16*)(base + 203554816);
    bf16*  g      = xcp;                        // xcp dead after G3
    bf16*  lf     = (bf16*)(base + 102891520);
    bf16*  globb  = confb;                      // confb dead after G3
    bf16*  vt     = (bf16*)(base + 138543104);
    bf16*  key    = (bf16*)(base + 139067392);
    bf16*  query  = (bf16*)(base + 155844608);
    bf16*  aff    = xpc;                        // xpc dead after G9
    bf16*  attn   = lf;                         // lf dead after G8

    bf16* wcam = wbf;
    bf16* wg2  = wbf + 262144;
    bf16* wq   = wbf + 524288;
    bf16* wk   = wbf + 655360;
    bf16* wv   = wbf + 786432;
    bf16* wo   = wbf + 917504;

    wconv<<<4096, 256, 0, stream>>>(w_cam, w_gcn2, w_q, w_k, w_v, w_out, wbf);
    convert_x<<<dim3(64, 16, 32), 256, 0, stream>>>(x, xpc, xcp);

    // 1) cam[bn][k][p] = w_cam . xpc + b_cam     M=512 N=1024 K=512 z=64
    gemm_bf16<0><<<4 * 8 * 64, 256, 0, stream>>>(
        (const short*)wcam, 0, (const short*)xpc, 524288, 0,
        (short*)confb, 524288, 512, 1024, 512, 4, 8, 64,
        b_cam, nullptr, nullptr, nullptr, nullptr, nullptr, nullptr, nullptr);
    // 2) pixel softmax (in place) + bin confidence
    softmax_pool_1024<<<32768, 256, 0, stream>>>(confb, bc);
    // 3) local[bn][k][c] = (conf . xcp) * bc     M=512 N=512 K=1024 z=64
    gemm_bf16<0><<<4 * 4 * 64, 256, 0, stream>>>(
        (const short*)confb, 524288, (const short*)xcp, 524288, 0,
        (short*)localb, 262144, 512, 512, 1024, 4, 4, 64,
        nullptr, nullptr, bc, nullptr, nullptr, nullptr, nullptr, nullptr);
    // 4) g = relu(w_gcn1 @ local + local)
    gcn1_kernel<<<4096, 256, 0, stream>>>(localb, g, w_gcn1);
    // 5) lfeats[bnk][d] = g . w_gcn2             M=32768 N=512 K=512 z=1
    gemm_bf16<0><<<256 * 4, 256, 0, stream>>>(
        (const short*)g, 0, (const short*)wg2, 0, 0,
        (short*)lf, 0, 32768, 512, 512, 256, 4, 1,
        nullptr, nullptr, nullptr, nullptr, nullptr, nullptr, nullptr, nullptr);
    // 6) glob = relu(w_fuse . lfeats + b_fuse)
    glob_kernel<<<4096, 256, 0, stream>>>(lf, globb, w_fuse, b_fuse);
    // 7) vt[b][i][k] = w_v . glob + b_v          M=256 N=512 K=512 z=4
    gemm_bf16<0><<<2 * 4 * 4, 256, 0, stream>>>(
        (const short*)wv, 0, (const short*)globb, 262144, 0,
        (short*)vt, 131072, 256, 512, 512, 2, 4, 4,
        b_v, nullptr, nullptr, nullptr, nullptr, nullptr, nullptr, nullptr);
    // 8) key[bnk][i] = lfeats . w_k + b_k        M=32768 N=256 K=512 z=1
    gemm_bf16<0><<<256 * 2, 256, 0, stream>>>(
        (const short*)lf, 0, (const short*)wk, 0, 0,
        (short*)key, 0, 32768, 256, 512, 256, 2, 1,
        nullptr, b_k, nullptr, nullptr, nullptr, nullptr, nullptr, nullptr);
    // 9) query[bn][p][i] = xpc . w_q + b_q       M=1024 N=256 K=512 z=64
    gemm_bf16<0><<<8 * 2 * 64, 256, 0, stream>>>(
        (const short*)xpc, 524288, (const short*)wq, 0, 0,
        (short*)query, 262144, 1024, 256, 512, 8, 2, 64,
        nullptr, b_q, nullptr, nullptr, nullptr, nullptr, nullptr, nullptr);
    // 10) aff[bn][p][k] = query . key            M=1024 N=512 K=256 z=64
    gemm_bf16<0><<<8 * 4 * 64, 256, 0, stream>>>(
        (const short*)query, 262144, (const short*)key, 131072, 0,
        (short*)aff, 524288, 1024, 512, 256, 8, 4, 64,
        nullptr, nullptr, nullptr, nullptr, nullptr, nullptr, nullptr, nullptr);
    // 11) softmax over k (in place)
    softmax_rows_512<<<16384, 256, 0, stream>>>(aff);
    // 12) attn[bn][p][i] = aff . vt[b]           M=1024 N=256 K=512 z=64
    gemm_bf16<0><<<8 * 2 * 64, 256, 0, stream>>>(
        (const short*)aff, 524288, (const short*)vt, 131072, 4,
        (short*)attn, 262144, 1024, 256, 512, 8, 2, 64,
        nullptr, nullptr, nullptr, nullptr, nullptr, nullptr, nullptr, nullptr);
    // 13) y = w_out . attn, fused BN+ReLU+residual, fp32 NCHW out
    //     M=512(c) N=1024(p) K=256 z=64
    gemm_bf16<1><<<4 * 8 * 64, 256, 0, stream>>>(
        (const short*)wo, 0, (const short*)attn, 262144, 0,
        (short*)d_out, 0, 512, 1024, 256, 4, 8, 64,
        nullptr, nullptr, nullptr, x, bng, bnb, bnm, bnv);
}